// Round 5
// baseline (207.148 us; speedup 1.0000x reference)
//
#include <hip/hip_runtime.h>

// YOLO v1 loss, two-kernel fused reduction.
// input_: [B, 30, 7, 7] fp32   (channel-major per image, 1470 floats/batch)
// target: [B, 7, 7, 30] fp32   (cell-major, also 1470 floats/batch)
// out   : [1] fp32 scalar loss
//
// Round-5: Rounds 3/4 proved per-thread register loads get serialized by the
// compiler (VGPR=36 => ~1 load in flight/wave, 1.4 TB/s, latency-bound).
// Fix: DMA both arrays block-linearly into LDS with global_load_lds (cannot
// be sunk/serialized; tracked on vmcnt), then compute from LDS.
// Block = 4 whole batches: 23520 B per array, 16B-aligned, grid divides B.

#define CELLF   64.0f
#define IMGF    448.0f
#define EPSF    1e-6f
#define LAMBDA_COORD 5.0f
#define LAMBDA_NOOBJ 0.5f

#define TPB        256
#define BPB        4                    // batches per block
#define CELLS_PB   (BPB * 49)           // 196 cells
#define FLOATS_PB  (BPB * 1470)         // 5880 floats per array per block
#define WBYTES     (FLOATS_PB * 4)      // 23520 bytes
#define NCHUNK     (WBYTES >> 10)       // 22 full 1024B wave-chunks
#define TAILOFF    (NCHUNK << 10)       // 22528
#define NTAILDW    ((WBYTES - TAILOFF) >> 2)   // 248 dwords

__global__ __launch_bounds__(TPB) void yolo_main(
    const float* __restrict__ input,
    const float* __restrict__ target,
    float* __restrict__ partial)
{
    __shared__ float s_in[FLOATS_PB];
    __shared__ float s_tg[FLOATS_PB];
    __shared__ float s_part[TPB / 64];

    const int tid  = threadIdx.x;
    const int wid  = tid >> 6;
    const int lane = tid & 63;

    const size_t base_f = (size_t)blockIdx.x * FLOATS_PB;
    const char* gin = (const char*)(input  + base_f);
    const char* gtg = (const char*)(target + base_f);

    // ---- DMA stage: 22 x 1024B chunks per array, round-robin over 4 waves ----
    for (int c = wid; c < NCHUNK; c += TPB / 64) {
        const int off = c << 10;
        __builtin_amdgcn_global_load_lds((const float*)(gin + off + lane * 16),
                                         (float*)((char*)s_in + off), 16, 0, 0);
        __builtin_amdgcn_global_load_lds((const float*)(gtg + off + lane * 16),
                                         (float*)((char*)s_tg + off), 16, 0, 0);
    }
    // tail: 248 dwords per array (size-4, lane-masked), one wave
    if (wid == (NCHUNK & 3)) {
        #pragma unroll
        for (int d = 0; d < NTAILDW; d += 64) {
            const int idx = d + lane;
            if (idx < NTAILDW) {
                __builtin_amdgcn_global_load_lds((const float*)(gin + TAILOFF + idx * 4),
                                                 (float*)((char*)s_in + TAILOFF + d * 4), 4, 0, 0);
                __builtin_amdgcn_global_load_lds((const float*)(gtg + TAILOFF + idx * 4),
                                                 (float*)((char*)s_tg + TAILOFF + d * 4), 4, 0, 0);
            }
        }
    }
    __syncthreads();   // drains vmcnt -> LDS valid

    // ---- compute from LDS ----
    float lv = 0.0f;
    if (tid < CELLS_PB) {
        const int db   = tid / 49;          // batch within block
        const int cell = tid - db * 49;
        const int row  = cell / 7;
        const int col  = cell - row * 7;

        const float* xin = s_in + db * 1470 + cell;   // stride-49 channel reads
        float x[30];
        #pragma unroll
        for (int c = 0; c < 30; ++c) x[c] = xin[c * 49];

        const float* t = s_tg + tid * 30;             // cell-contiguous
        float tt[30];
        #pragma unroll
        for (int j = 0; j < 30; ++j) tt[j] = t[j];

        const float colf = (float)col * CELLF;
        const float rowf = (float)row * CELLF;

        float iou[2];
        #pragma unroll
        for (int k = 0; k < 2; ++k) {
            const int o = 5 * k;
            float pcx = x[o + 0] * CELLF + colf;
            float pcy = x[o + 1] * CELLF + rowf;
            float pw  = x[o + 2] * IMGF;
            float ph  = x[o + 3] * IMGF;
            float px1 = fminf(fmaxf(pcx - 0.5f * pw, 0.0f), IMGF);
            float py1 = fminf(fmaxf(pcy - 0.5f * ph, 0.0f), IMGF);
            float px2 = fminf(fmaxf(pcx + 0.5f * pw, 0.0f), IMGF);
            float py2 = fminf(fmaxf(pcy + 0.5f * ph, 0.0f), IMGF);

            float tcx = tt[o + 0] * CELLF + colf;
            float tcy = tt[o + 1] * CELLF + rowf;
            float tw  = tt[o + 2] * IMGF;
            float th  = tt[o + 3] * IMGF;
            float tx1 = fminf(fmaxf(tcx - 0.5f * tw, 0.0f), IMGF);
            float ty1 = fminf(fmaxf(tcy - 0.5f * th, 0.0f), IMGF);
            float tx2 = fminf(fmaxf(tcx + 0.5f * tw, 0.0f), IMGF);
            float ty2 = fminf(fmaxf(tcy + 0.5f * th, 0.0f), IMGF);

            float iw = fmaxf(fminf(px2, tx2) - fmaxf(px1, tx1), EPSF);
            float ih = fmaxf(fminf(py2, ty2) - fmaxf(py1, ty1), EPSF);
            float inter = iw * ih;
            float area  = (px2 - px1) * (py2 - py1) + (tx2 - tx1) * (ty2 - ty1);
            iou[k] = inter / (area - inter);
        }

        const bool  m      = iou[0] < iou[1];
        const float iouSel = m ? iou[1] : iou[0];
        const float has_obj = (tt[4] == 1.0f) ? 1.0f : 0.0f;
        const float no_obj  = 1.0f - has_obj;

        const float s0 = m ? x[5] : x[0];
        const float s1 = m ? x[6] : x[1];
        const float s2 = m ? x[7] : x[2];
        const float s3 = m ? x[8] : x[3];
        const float s4 = m ? x[9] : x[4];

        float d0 = s0 - tt[0], d1 = s1 - tt[1];
        float coord_e = d0 * d0 + d1 * d1;

        float e2 = sqrtf(s2) - sqrtf(tt[2]);
        float e3 = sqrtf(s3) - sqrtf(tt[3]);
        float size_e = e2 * e2 + e3 * e3;

        float dc = s4 - iouSel;
        float conf_e = dc * dc;

        float cls_e = 0.0f;
        #pragma unroll
        for (int c = 10; c < 30; ++c) {
            float d = x[c] - tt[c];
            cls_e += d * d;
        }

        float noobj_e = x[4] * x[4] + x[9] * x[9];

        lv = has_obj * (LAMBDA_COORD * coord_e + LAMBDA_COORD * size_e + conf_e + cls_e)
           + LAMBDA_NOOBJ * no_obj * noobj_e;
    }

    // ---- reduce: wave shuffle, then cross-wave via LDS ----
    #pragma unroll
    for (int off = 32; off > 0; off >>= 1)
        lv += __shfl_down(lv, off, 64);

    if ((tid & 63) == 0) s_part[tid >> 6] = lv;
    __syncthreads();

    if (tid == 0) {
        float tot = 0.0f;
        #pragma unroll
        for (int w = 0; w < TPB / 64; ++w) tot += s_part[w];
        partial[blockIdx.x] = tot;
    }
}

__global__ __launch_bounds__(256) void yolo_reduce(
    const float* __restrict__ partial, int nparts,
    float* __restrict__ out, float inv_b)
{
    const int tid = threadIdx.x;
    float v = 0.0f;
    for (int i = tid; i < nparts; i += 256) v += partial[i];

    #pragma unroll
    for (int off = 32; off > 0; off >>= 1)
        v += __shfl_down(v, off, 64);

    __shared__ float s_part[4];
    if ((tid & 63) == 0) s_part[tid >> 6] = v;
    __syncthreads();

    if (tid == 0)
        out[0] = (s_part[0] + s_part[1] + s_part[2] + s_part[3]) * inv_b;
}

extern "C" void kernel_launch(void* const* d_in, const int* in_sizes, int n_in,
                              void* d_out, int out_size, void* d_ws, size_t ws_size,
                              hipStream_t stream) {
    const float* input  = (const float*)d_in[0];
    const float* target = (const float*)d_in[1];
    float* out = (float*)d_out;
    float* partial = (float*)d_ws;

    const int B = in_sizes[0] / (30 * 49);   // 16384
    const int nblocks = B / BPB;             // 4096 (B divisible by 4)

    yolo_main<<<nblocks, TPB, 0, stream>>>(input, target, partial);
    yolo_reduce<<<1, 256, 0, stream>>>(partial, nblocks, out, 1.0f / (float)B);
}